// Round 14
// baseline (59.285 us; speedup 1.0000x reference)
//
#include <hip/hip_runtime.h>
#include <math.h>

#define NB 2
#define NTOK 16384
#define CDIM 64
#define WIMG 128
#define NKV 256
#define NHEAD 8
#define HDIM 8
#define RTOKS 512   // NB*NKV reduced tokens
#define NSLICE 32   // conv partial slices (16 kchunks x 2 tap-pairs)

typedef unsigned short u16;
typedef __attribute__((ext_vector_type(8))) short bf16x8;
typedef __attribute__((ext_vector_type(4))) unsigned int u32x4;
typedef __attribute__((ext_vector_type(2))) unsigned int u32x2;
typedef __attribute__((ext_vector_type(16))) float f32x16;

// softmax scale folded with log2(e), applied to K before bf16 quantization
constexpr float KSCALE = 0.35355339059327373f * 1.4426950408889634f;

__device__ __forceinline__ u16 f2bf(float f) {   // RNE f32->bf16
  unsigned u = __builtin_bit_cast(unsigned, f);
  return (u16)((u + 0x7FFFu + ((u >> 16) & 1u)) >> 16);
}
__device__ __forceinline__ float bf2f(u16 h) {
  return __builtin_bit_cast(float, (unsigned)h << 16);
}

__device__ __forceinline__ f32x16 mfma32x16(bf16x8 a, bf16x8 b, f32x16 c) {
  return __builtin_amdgcn_mfma_f32_32x32x16_bf16(a, b, c, 0, 0, 0);
}

__device__ __forceinline__ void pl32swap(unsigned &a, unsigned &b) {
  u32x2 r = __builtin_amdgcn_permlane32_swap(a, b, false, false);
  a = r[0]; b = r[1];
}

__device__ __forceinline__ float fexp2(float x) {
  float r;
  asm("v_exp_f32 %0, %1" : "=v"(r) : "v"(x));
  return r;
}

// split 8 f32 into hi/lo bf16 fragments: v ~= hi + lo
__device__ __forceinline__ void split8(const float* v, bf16x8& hout, bf16x8& lout) {
  unsigned hw[4], lw[4];
  float hf[8], lof[8];
  #pragma unroll
  for (int q = 0; q < 4; ++q)
    asm("v_cvt_pk_bf16_f32 %0, %1, %2" : "=v"(hw[q]) : "v"(v[2*q]), "v"(v[2*q+1]));
  #pragma unroll
  for (int q = 0; q < 4; ++q) {
    hf[2*q]   = __builtin_bit_cast(float, hw[q] << 16);
    hf[2*q+1] = __builtin_bit_cast(float, hw[q] & 0xFFFF0000u);
  }
  #pragma unroll
  for (int j = 0; j < 8; ++j) lof[j] = v[j] - hf[j];
  #pragma unroll
  for (int q = 0; q < 4; ++q)
    asm("v_cvt_pk_bf16_f32 %0, %1, %2" : "=v"(lw[q]) : "v"(lof[2*q]), "v"(lof[2*q+1]));
  u32x4 H; H[0] = hw[0]; H[1] = hw[1]; H[2] = hw[2]; H[3] = hw[3];
  u32x4 L; L[0] = lw[0]; L[1] = lw[1]; L[2] = lw[2]; L[3] = lw[3];
  hout = __builtin_bit_cast(bf16x8, H);
  lout = __builtin_bit_cast(bf16x8, L);
}

__device__ __forceinline__ float wave_reduce_sum64(float v) {
  #pragma unroll
  for (int off = 32; off > 0; off >>= 1) v += __shfl_xor(v, off, 64);
  return v;
}

// ---------------- k0p: pack all weights into MFMA-B-operand bf16 hi/lo layouts.
__global__ __launch_bounds__(256) void k0_pack(const float* __restrict__ srw,
                                               const float* __restrict__ qw,
                                               const float* __restrict__ pw,
                                               u16* __restrict__ wpk_hi, u16* __restrict__ wpk_lo,
                                               u16* __restrict__ qpk_hi, u16* __restrict__ qpk_lo,
                                               u16* __restrict__ ppk_hi, u16* __restrict__ ppk_lo) {
  int idx = blockIdx.x * 256 + threadIdx.x;   // 270336 total = 1056*256
  if (idx < 262144) {
    const int j   = idx & 7;
    const int oc  = (idx >> 3) & 63;
    const int hi  = (idx >> 9) & 1;
    const int icg = (idx >> 10) & 3;
    const int s   = idx >> 12;
    const float v = srw[oc * 4096 + (icg * 16 + hi * 8 + j) * 64 + s];
    const u16 h = f2bf(v);
    wpk_hi[idx] = h;
    wpk_lo[idx] = f2bf(v - bf2f(h));
  } else if (idx < 262144 + 4096) {
    const int q = idx - 262144;
    const int j   = q & 7;
    const int o   = (q >> 3) & 63;
    const int hi  = (q >> 9) & 1;
    const int icg = q >> 10;
    const float v = qw[(icg * 16 + hi * 8 + j) * 64 + o];
    const u16 h = f2bf(v);
    qpk_hi[q] = h;
    qpk_lo[q] = f2bf(v - bf2f(h));
  } else if (idx < 262144 + 8192) {
    const int q = idx - 262144 - 4096;
    const int j  = q & 7;
    const int o  = (q >> 3) & 63;
    const int hi = (q >> 9) & 1;
    const int g  = q >> 10;
    const float v = pw[(g * 16 + hi * 8 + j) * 64 + o];
    const u16 h = f2bf(v);
    ppk_hi[q] = h;
    ppk_lo[q] = f2bf(v - bf2f(h));
  }
}

// ---------------- kA2: conv partials via split-bf16 MFMA, coalesced packed weights.
__global__ __launch_bounds__(256) void kA2_conv(const float* __restrict__ x,
                                                const u16* __restrict__ wpk_hi,
                                                const u16* __restrict__ wpk_lo,
                                                float* __restrict__ pbuf) {
  const int t = threadIdx.x;
  const int lane = t & 63;
  const int lo = lane & 31;
  const int hi = lane >> 5;
  const int w = t >> 6;
  const int oc0 = (w & 1) * 32;
  const int th = w >> 1;                  // tap-pair within chunk
  const int tile = blockIdx.x;
  const int kc = blockIdx.y;
  const int tg = tile * 32 + lo;          // reduced token (A-row m)
  const int b = tg >> 8;
  const int p = tg & 255;

  f32x16 c;
  #pragma unroll
  for (int i = 0; i < 16; ++i) c[i] = 0.f;

  #pragma unroll
  for (int sp = 0; sp < 2; ++sp) {
    const int s = kc * 4 + th * 2 + sp;   // conv tap 0..63
    const int kh = s >> 3, kw = s & 7;
    const int nrow = ((p >> 4) * 8 + kh) * WIMG + (p & 15) * 8 + kw;
    const float* xr = x + ((size_t)b * NTOK + nrow) * CDIM;
    #pragma unroll
    for (int icg = 0; icg < 4; ++icg) {
      const int ic0 = icg * 16 + hi * 8;
      float4 a0 = *(const float4*)(xr + ic0);
      float4 a1 = *(const float4*)(xr + ic0 + 4);
      float v[8] = {a0.x, a0.y, a0.z, a0.w, a1.x, a1.y, a1.z, a1.w};
      bf16x8 ah, al;
      split8(v, ah, al);
      const size_t widx = ((((size_t)s * 4 + icg) * 2 + hi) * 64 + (oc0 + lo)) * 8;
      bf16x8 bh = *(const bf16x8*)(wpk_hi + widx);
      bf16x8 bl = *(const bf16x8*)(wpk_lo + widx);
      c = mfma32x16(ah, bh, c);
      c = mfma32x16(ah, bl, c);
      c = mfma32x16(al, bh, c);
    }
  }
  const int slice = kc * 2 + th;
  #pragma unroll
  for (int r = 0; r < 16; ++r) {
    const int tokr = (r & 3) + 8 * (r >> 2) + 4 * hi;   // verified C row map
    pbuf[((size_t)slice * RTOKS + tile * 32 + tokr) * 64 + oc0 + lo] = c[r];
  }
}

// ---------------- K2: reduce 32 slices + bias + LN + KV proj -> bf16 K (scaled), bf16 V^T
__global__ __launch_bounds__(64) void k2_ln_kv(const float* __restrict__ pbuf,
                                               const float* __restrict__ srb,
                                               const float* __restrict__ lng,
                                               const float* __restrict__ lnb,
                                               const float* __restrict__ kvw,
                                               u16* __restrict__ kbuf,
                                               u16* __restrict__ vbufT) {
  __shared__ float ylds[64];
  const int tg = blockIdx.x;    // 0..511 reduced token
  const int o  = threadIdx.x;   // 0..63 channel
  float y = srb[o];
  #pragma unroll 8
  for (int s = 0; s < NSLICE; ++s) y += pbuf[((size_t)s * RTOKS + tg) * 64 + o];
  const float sum   = wave_reduce_sum64(y);
  const float sumsq = wave_reduce_sum64(y * y);
  const float mu  = sum * (1.f / 64.f);
  const float var = sumsq * (1.f / 64.f) - mu * mu;
  const float rstd = rsqrtf(var + 1e-5f);
  const float yn = (y - mu) * rstd * lng[o] + lnb[o];
  ylds[o] = yn;
  __syncthreads();
  float ka = 0.f, va = 0.f;
  #pragma unroll 16
  for (int i = 0; i < 64; ++i) {
    const float yv = ylds[i];
    ka += yv * kvw[i * 128 + o];
    va += yv * kvw[i * 128 + 64 + o];
  }
  const int b = tg >> 8, pp = tg & 255;
  const int h = o >> 3, d = o & 7;
  const int bh = b * NHEAD + h;
  kbuf[((size_t)bh * NKV + pp) * HDIM + d] = f2bf(ka * KSCALE);
  vbufT[((size_t)bh * HDIM + d) * NKV + pp] = f2bf(va);
}

// ---------------- kQ: q = x @ qw via split-bf16 MFMA -> bf16 qbuf [B][H][N][8].
__global__ __launch_bounds__(256) void kQ_qproj(const float* __restrict__ x,
                                                const u16* __restrict__ qpk_hi,
                                                const u16* __restrict__ qpk_lo,
                                                u16* __restrict__ qbuf) {
  const int t = threadIdx.x;
  const int lane = t & 63;
  const int lo = lane & 31;
  const int hi = lane >> 5;
  const int w = t >> 6;
  const int oc0 = (w & 1) * 32;
  const int blk = blockIdx.x;
  const int b = blk >> 8;
  const int tok0 = ((blk & 255) * 2 + (w >> 1)) * 32;

  f32x16 c;
  #pragma unroll
  for (int i = 0; i < 16; ++i) c[i] = 0.f;

  const float* xr = x + ((size_t)b * NTOK + tok0 + lo) * CDIM;
  #pragma unroll
  for (int icg = 0; icg < 4; ++icg) {
    const int ic0 = icg * 16 + hi * 8;
    float4 a0 = *(const float4*)(xr + ic0);
    float4 a1 = *(const float4*)(xr + ic0 + 4);
    float v[8] = {a0.x, a0.y, a0.z, a0.w, a1.x, a1.y, a1.z, a1.w};
    bf16x8 ah, al;
    split8(v, ah, al);
    const size_t qidx = (((size_t)icg * 2 + hi) * 64 + (oc0 + lo)) * 8;
    bf16x8 bh = *(const bf16x8*)(qpk_hi + qidx);
    bf16x8 bl = *(const bf16x8*)(qpk_lo + qidx);
    c = mfma32x16(ah, bh, c);
    c = mfma32x16(ah, bl, c);
    c = mfma32x16(al, bh, c);
  }
  const int oc = oc0 + lo;
  const int h = oc >> 3, d = oc & 7;
  u16* qb = qbuf + (((size_t)b * NHEAD + h) * NTOK) * HDIM + d;
  #pragma unroll
  for (int r = 0; r < 16; ++r) {
    const int tok = tok0 + (r & 3) + 8 * (r >> 2) + 4 * hi;
    qb[(size_t)tok * HDIM] = f2bf(c[r]);
  }
}

// ---------------- K4 v8 (r13): twin-tile interleave, ones-row denominator.
__global__ __launch_bounds__(256) void k4_attn_mfma(const u16* __restrict__ qbuf,
                                                    const u16* __restrict__ kbuf,
                                                    const u16* __restrict__ vbufT,
                                                    float* __restrict__ abuf) {
  const int t = threadIdx.x;
  const int lane = t & 63;
  const int w = blockIdx.x * 4 + (t >> 6);   // global wave id, 0..2047
  const int bh = w >> 7;                     // 16 (b,h) pairs, 128 waves each
  const int wi = w & 127;
  const int lo = lane & 31;
  const int hi = lane >> 5;

  bf16x8 kf[8];
  const u16* kb = kbuf + (size_t)bh * NKV * HDIM;
  #pragma unroll
  for (int c = 0; c < 8; ++c) {
    bf16x8 z = {0, 0, 0, 0, 0, 0, 0, 0};
    if (hi == 0) z = *(const bf16x8*)(kb + (c * 32 + lo) * HDIM);
    kf[c] = z;
  }

  const short one_bf = (short)0x3F80;
  bf16x8 vf[16];
  const u16* vb = vbufT + (size_t)bh * HDIM * NKV;
  #pragma unroll
  for (int f = 0; f < 16; ++f) {
    bf16x8 z = {0, 0, 0, 0, 0, 0, 0, 0};
    if (lo < 8) {
      z = *(const bf16x8*)(vb + lo * NKV + f * 16 + hi * 8);
    } else if (lo == 8) {
      bf16x8 o1 = {one_bf, one_bf, one_bf, one_bf, one_bf, one_bf, one_bf, one_bf};
      z = o1;
    }
    vf[f] = z;
  }

  #pragma unroll
  for (int cp = 0; cp < 2; ++cp) {
    const int qtA = (wi * 4 + cp * 2) * 32;
    const int qtB = qtA + 32;
    bf16x8 qfA = {0, 0, 0, 0, 0, 0, 0, 0};
    bf16x8 qfB = {0, 0, 0, 0, 0, 0, 0, 0};
    if (hi == 0) {
      qfA = *(const bf16x8*)(qbuf + ((size_t)bh * NTOK + qtA + lo) * HDIM);
      qfB = *(const bf16x8*)(qbuf + ((size_t)bh * NTOK + qtB + lo) * HDIM);
    }

    f32x16 oA, oB;
    #pragma unroll
    for (int i = 0; i < 16; ++i) { oA[i] = 0.f; oB[i] = 0.f; }

    #pragma unroll
    for (int kblk = 0; kblk < 8; ++kblk) {
      f32x16 sA, sB;
      #pragma unroll
      for (int i = 0; i < 16; ++i) { sA[i] = 0.f; sB[i] = 0.f; }
      sA = mfma32x16(kf[kblk], qfA, sA);
      sB = mfma32x16(kf[kblk], qfB, sB);

      #pragma unroll
      for (int r = 0; r < 16; ++r) sA[r] = fexp2(sA[r]);
      #pragma unroll
      for (int r = 0; r < 16; ++r) sB[r] = fexp2(sB[r]);

      unsigned pkA01[4], pkA23[4], pkB01[4], pkB23[4];
      #pragma unroll
      for (int q = 0; q < 4; ++q) {
        asm("v_cvt_pk_bf16_f32 %0, %1, %2" : "=v"(pkA01[q]) : "v"(sA[4*q+0]), "v"(sA[4*q+1]));
        asm("v_cvt_pk_bf16_f32 %0, %1, %2" : "=v"(pkA23[q]) : "v"(sA[4*q+2]), "v"(sA[4*q+3]));
      }
      #pragma unroll
      for (int q = 0; q < 4; ++q) {
        asm("v_cvt_pk_bf16_f32 %0, %1, %2" : "=v"(pkB01[q]) : "v"(sB[4*q+0]), "v"(sB[4*q+1]));
        asm("v_cvt_pk_bf16_f32 %0, %1, %2" : "=v"(pkB23[q]) : "v"(sB[4*q+2]), "v"(sB[4*q+3]));
      }
      #pragma unroll
      for (int jj = 0; jj < 2; ++jj) {
        unsigned a0 = pkA01[2*jj], b0 = pkA01[2*jj+1];
        unsigned a1 = pkA23[2*jj], b1 = pkA23[2*jj+1];
        pl32swap(a0, b0);
        pl32swap(a1, b1);
        u32x4 wv; wv[0] = a0; wv[1] = a1; wv[2] = b0; wv[3] = b1;
        bf16x8 pfrag = __builtin_bit_cast(bf16x8, wv);
        oA = mfma32x16(vf[kblk * 2 + jj], pfrag, oA);
      }
      #pragma unroll
      for (int jj = 0; jj < 2; ++jj) {
        unsigned a0 = pkB01[2*jj], b0 = pkB01[2*jj+1];
        unsigned a1 = pkB23[2*jj], b1 = pkB23[2*jj+1];
        pl32swap(a0, b0);
        pl32swap(a1, b1);
        u32x4 wv; wv[0] = a0; wv[1] = a1; wv[2] = b0; wv[3] = b1;
        bf16x8 pfrag = __builtin_bit_cast(bf16x8, wv);
        oB = mfma32x16(vf[kblk * 2 + jj], pfrag, oB);
      }
    }

    {
      float d0 = oA[4];
      float d1 = __shfl_xor(d0, 32, 64);
      const float den = hi ? d1 : d0;
      const float r = 1.0f / den;
      float4 o;
      o.x = oA[0] * r; o.y = oA[1] * r; o.z = oA[2] * r; o.w = oA[3] * r;
      *(float4*)(abuf + ((size_t)bh * NTOK + qtA + lo) * HDIM + hi * 4) = o;
    }
    {
      float d0 = oB[4];
      float d1 = __shfl_xor(d0, 32, 64);
      const float den = hi ? d1 : d0;
      const float r = 1.0f / den;
      float4 o;
      o.x = oB[0] * r; o.y = oB[1] * r; o.z = oB[2] * r; o.w = oB[3] * r;
      *(float4*)(abuf + ((size_t)bh * NTOK + qtB + lo) * HDIM + hi * 4) = o;
    }
  }
}

// ---------------- kP: out = O @ pw + pb via split-bf16 MFMA.
__global__ __launch_bounds__(256) void kP_proj(const float* __restrict__ abuf,
                                               const u16* __restrict__ ppk_hi,
                                               const u16* __restrict__ ppk_lo,
                                               const float* __restrict__ pb,
                                               float* __restrict__ out) {
  const int t = threadIdx.x;
  const int lane = t & 63;
  const int lo = lane & 31;
  const int hi = lane >> 5;
  const int w = t >> 6;
  const int oc0 = (w & 1) * 32;
  const int blk = blockIdx.x;
  const int b = blk >> 8;
  const int tok0 = ((blk & 255) * 2 + (w >> 1)) * 32;

  f32x16 c;
  #pragma unroll
  for (int i = 0; i < 16; ++i) c[i] = 0.f;

  #pragma unroll
  for (int f = 0; f < 4; ++f) {
    const int h = 2 * f + hi;                 // attention-output channel group = head
    const float* src = abuf + (((size_t)b * NHEAD + h) * NTOK + tok0 + lo) * HDIM;
    float4 a0 = *(const float4*)(src);
    float4 a1 = *(const float4*)(src + 4);
    float v[8] = {a0.x, a0.y, a0.z, a0.w, a1.x, a1.y, a1.z, a1.w};
    bf16x8 ah, al;
    split8(v, ah, al);
    const size_t pidx = (((size_t)f * 2 + hi) * 64 + (oc0 + lo)) * 8;
    bf16x8 bh = *(const bf16x8*)(ppk_hi + pidx);
    bf16x8 bl = *(const bf16x8*)(ppk_lo + pidx);
    c = mfma32x16(ah, bh, c);
    c = mfma32x16(ah, bl, c);
    c = mfma32x16(al, bh, c);
  }
  const float pbv = pb[oc0 + lo];
  #pragma unroll
  for (int r = 0; r < 16; ++r) {
    const int tok = tok0 + (r & 3) + 8 * (r >> 2) + 4 * hi;
    out[((size_t)b * NTOK + tok) * CDIM + oc0 + lo] = c[r] + pbv;
  }
}

extern "C" void kernel_launch(void* const* d_in, const int* in_sizes, int n_in,
                              void* d_out, int out_size, void* d_ws, size_t ws_size,
                              hipStream_t stream) {
  const float* x    = (const float*)d_in[0];
  // d_in[1], d_in[2] are H, W scalars (128, 128) — fixed by the problem
  const float* qw   = (const float*)d_in[3];
  const float* kvw  = (const float*)d_in[4];
  const float* srw  = (const float*)d_in[5];
  const float* srb  = (const float*)d_in[6];
  const float* lng  = (const float*)d_in[7];
  const float* lnb  = (const float*)d_in[8];
  const float* pw   = (const float*)d_in[9];
  const float* pb   = (const float*)d_in[10];
  float* out = (float*)d_out;
  char* base = (char*)d_ws;

  u16*   wpk_hi = (u16*)(base);               // 524288 B
  u16*   wpk_lo = (u16*)(base + 524288);      // 524288 B
  u16*   qpk_hi = (u16*)(base + 1048576);     // 8192 B
  u16*   qpk_lo = (u16*)(base + 1056768);     // 8192 B
  u16*   ppk_hi = (u16*)(base + 1064960);     // 8192 B
  u16*   ppk_lo = (u16*)(base + 1073152);     // 8192 B
  float* pbuf   = (float*)(base + 1081344);   // 32*512*64 f32 = 4194304 B
  u16*   kbuf   = (u16*)(base + 5275648);     // 65536 B
  u16*   vbufT  = (u16*)(base + 5341184);     // 65536 B
  u16*   qbuf   = (u16*)(base + 5406720);     // 4194304 B
  float* abuf   = (float*)(base + 9601024);   // 8388608 B
  float* abuf2  = (float*)(base + 17989632);  // 8388608 B scratch (k4 timer probe)

  k0_pack<<<1056, 256, 0, stream>>>(srw, qw, pw, wpk_hi, wpk_lo,
                                    qpk_hi, qpk_lo, ppk_hi, ppk_lo);
  kA2_conv<<<dim3(16, 16), 256, 0, stream>>>(x, wpk_hi, wpk_lo, pbuf);
  k2_ln_kv<<<512, 64, 0, stream>>>(pbuf, srb, lng, lnb, kvw, kbuf, vbufT);
  kQ_qproj<<<512, 256, 0, stream>>>(x, qpk_hi, qpk_lo, qbuf);
  k4_attn_mfma<<<512, 256, 0, stream>>>(qbuf, kbuf, vbufT, abuf);
  kP_proj<<<512, 256, 0, stream>>>(abuf, ppk_hi, ppk_lo, pb, out);
  // ---- measurement probe: byte-identical k4 re-run into scratch (output unused).
  // dur_us delta vs r13 == k4 duration + one graph gap. Deterministic & idempotent.
  k4_attn_mfma<<<512, 256, 0, stream>>>(qbuf, kbuf, vbufT, abuf2);
}

// Round 15
// 42.009 us; speedup vs baseline: 1.4112x; 1.4112x over previous
//
#include <hip/hip_runtime.h>
#include <math.h>

#define NB 2
#define NTOK 16384
#define CDIM 64
#define WIMG 128
#define NKV 256
#define NHEAD 8
#define HDIM 8
#define RTOKS 512   // NB*NKV reduced tokens
#define NSLICE 32   // conv partial slices (16 kchunks x 2 tap-pairs)

typedef unsigned short u16;
typedef __attribute__((ext_vector_type(8))) short bf16x8;
typedef __attribute__((ext_vector_type(4))) unsigned int u32x4;
typedef __attribute__((ext_vector_type(2))) unsigned int u32x2;
typedef __attribute__((ext_vector_type(16))) float f32x16;

// softmax scale folded with log2(e), applied to K before bf16 quantization
constexpr float KSCALE = 0.35355339059327373f * 1.4426950408889634f;

__device__ __forceinline__ u16 f2bf(float f) {   // RNE f32->bf16
  unsigned u = __builtin_bit_cast(unsigned, f);
  return (u16)((u + 0x7FFFu + ((u >> 16) & 1u)) >> 16);
}
__device__ __forceinline__ float bf2f(u16 h) {
  return __builtin_bit_cast(float, (unsigned)h << 16);
}

__device__ __forceinline__ f32x16 mfma32x16(bf16x8 a, bf16x8 b, f32x16 c) {
  return __builtin_amdgcn_mfma_f32_32x32x16_bf16(a, b, c, 0, 0, 0);
}

__device__ __forceinline__ void pl32swap(unsigned &a, unsigned &b) {
  u32x2 r = __builtin_amdgcn_permlane32_swap(a, b, false, false);
  a = r[0]; b = r[1];
}

__device__ __forceinline__ float fexp2(float x) {
  float r;
  asm("v_exp_f32 %0, %1" : "=v"(r) : "v"(x));
  return r;
}

// split 8 f32 into hi/lo bf16 fragments: v ~= hi + lo
__device__ __forceinline__ void split8(const float* v, bf16x8& hout, bf16x8& lout) {
  unsigned hw[4], lw[4];
  float hf[8], lof[8];
  #pragma unroll
  for (int q = 0; q < 4; ++q)
    asm("v_cvt_pk_bf16_f32 %0, %1, %2" : "=v"(hw[q]) : "v"(v[2*q]), "v"(v[2*q+1]));
  #pragma unroll
  for (int q = 0; q < 4; ++q) {
    hf[2*q]   = __builtin_bit_cast(float, hw[q] << 16);
    hf[2*q+1] = __builtin_bit_cast(float, hw[q] & 0xFFFF0000u);
  }
  #pragma unroll
  for (int j = 0; j < 8; ++j) lof[j] = v[j] - hf[j];
  #pragma unroll
  for (int q = 0; q < 4; ++q)
    asm("v_cvt_pk_bf16_f32 %0, %1, %2" : "=v"(lw[q]) : "v"(lof[2*q]), "v"(lof[2*q+1]));
  u32x4 H; H[0] = hw[0]; H[1] = hw[1]; H[2] = hw[2]; H[3] = hw[3];
  u32x4 L; L[0] = lw[0]; L[1] = lw[1]; L[2] = lw[2]; L[3] = lw[3];
  hout = __builtin_bit_cast(bf16x8, H);
  lout = __builtin_bit_cast(bf16x8, L);
}

__device__ __forceinline__ float wave_reduce_sum64(float v) {
  #pragma unroll
  for (int off = 32; off > 0; off >>= 1) v += __shfl_xor(v, off, 64);
  return v;
}

// ---------------- k0p: pack all weights into MFMA-B-operand bf16 hi/lo layouts.
__global__ __launch_bounds__(256) void k0_pack(const float* __restrict__ srw,
                                               const float* __restrict__ qw,
                                               const float* __restrict__ pw,
                                               u16* __restrict__ wpk_hi, u16* __restrict__ wpk_lo,
                                               u16* __restrict__ qpk_hi, u16* __restrict__ qpk_lo,
                                               u16* __restrict__ ppk_hi, u16* __restrict__ ppk_lo) {
  int idx = blockIdx.x * 256 + threadIdx.x;   // 270336 total = 1056*256
  if (idx < 262144) {
    const int j   = idx & 7;
    const int oc  = (idx >> 3) & 63;
    const int hi  = (idx >> 9) & 1;
    const int icg = (idx >> 10) & 3;
    const int s   = idx >> 12;
    const float v = srw[oc * 4096 + (icg * 16 + hi * 8 + j) * 64 + s];
    const u16 h = f2bf(v);
    wpk_hi[idx] = h;
    wpk_lo[idx] = f2bf(v - bf2f(h));
  } else if (idx < 262144 + 4096) {
    const int q = idx - 262144;
    const int j   = q & 7;
    const int o   = (q >> 3) & 63;
    const int hi  = (q >> 9) & 1;
    const int icg = q >> 10;
    const float v = qw[(icg * 16 + hi * 8 + j) * 64 + o];
    const u16 h = f2bf(v);
    qpk_hi[q] = h;
    qpk_lo[q] = f2bf(v - bf2f(h));
  } else if (idx < 262144 + 8192) {
    const int q = idx - 262144 - 4096;
    const int j  = q & 7;
    const int o  = (q >> 3) & 63;
    const int hi = (q >> 9) & 1;
    const int g  = q >> 10;
    const float v = pw[(g * 16 + hi * 8 + j) * 64 + o];
    const u16 h = f2bf(v);
    ppk_hi[q] = h;
    ppk_lo[q] = f2bf(v - bf2f(h));
  }
}

// ---------------- kAQ: merged conv-partials + q-proj (independent after k0p).
// blocks 0..255: conv (tile = blk&15, kc = blk>>4). blocks 256..767: q-proj.
__global__ __launch_bounds__(256) void kAQ_conv_qproj(const float* __restrict__ x,
                                                      const u16* __restrict__ wpk_hi,
                                                      const u16* __restrict__ wpk_lo,
                                                      const u16* __restrict__ qpk_hi,
                                                      const u16* __restrict__ qpk_lo,
                                                      float* __restrict__ pbuf,
                                                      u16* __restrict__ qbuf) {
  const int t = threadIdx.x;
  const int lane = t & 63;
  const int lo = lane & 31;
  const int hi = lane >> 5;
  const int w = t >> 6;
  const int oc0 = (w & 1) * 32;
  const int blk = blockIdx.x;

  if (blk < 256) {
    // ---- conv partials (r13 kA2 verbatim math)
    const int th = w >> 1;                  // tap-pair within chunk
    const int tile = blk & 15;
    const int kc = blk >> 4;
    const int tg = tile * 32 + lo;          // reduced token (A-row m)
    const int b = tg >> 8;
    const int p = tg & 255;

    f32x16 c;
    #pragma unroll
    for (int i = 0; i < 16; ++i) c[i] = 0.f;

    #pragma unroll
    for (int sp = 0; sp < 2; ++sp) {
      const int s = kc * 4 + th * 2 + sp;   // conv tap 0..63
      const int kh = s >> 3, kw = s & 7;
      const int nrow = ((p >> 4) * 8 + kh) * WIMG + (p & 15) * 8 + kw;
      const float* xr = x + ((size_t)b * NTOK + nrow) * CDIM;
      #pragma unroll
      for (int icg = 0; icg < 4; ++icg) {
        const int ic0 = icg * 16 + hi * 8;
        float4 a0 = *(const float4*)(xr + ic0);
        float4 a1 = *(const float4*)(xr + ic0 + 4);
        float v[8] = {a0.x, a0.y, a0.z, a0.w, a1.x, a1.y, a1.z, a1.w};
        bf16x8 ah, al;
        split8(v, ah, al);
        const size_t widx = ((((size_t)s * 4 + icg) * 2 + hi) * 64 + (oc0 + lo)) * 8;
        bf16x8 bh = *(const bf16x8*)(wpk_hi + widx);
        bf16x8 bl = *(const bf16x8*)(wpk_lo + widx);
        c = mfma32x16(ah, bh, c);
        c = mfma32x16(ah, bl, c);
        c = mfma32x16(al, bh, c);
      }
    }
    const int slice = kc * 2 + th;
    #pragma unroll
    for (int r = 0; r < 16; ++r) {
      const int tokr = (r & 3) + 8 * (r >> 2) + 4 * hi;   // verified C row map
      pbuf[((size_t)slice * RTOKS + tile * 32 + tokr) * 64 + oc0 + lo] = c[r];
    }
  } else {
    // ---- q-proj (r13 kQ verbatim math)
    const int qblk = blk - 256;             // 0..511
    const int b = qblk >> 8;
    const int tok0 = ((qblk & 255) * 2 + (w >> 1)) * 32;

    f32x16 c;
    #pragma unroll
    for (int i = 0; i < 16; ++i) c[i] = 0.f;

    const float* xr = x + ((size_t)b * NTOK + tok0 + lo) * CDIM;
    #pragma unroll
    for (int icg = 0; icg < 4; ++icg) {
      const int ic0 = icg * 16 + hi * 8;
      float4 a0 = *(const float4*)(xr + ic0);
      float4 a1 = *(const float4*)(xr + ic0 + 4);
      float v[8] = {a0.x, a0.y, a0.z, a0.w, a1.x, a1.y, a1.z, a1.w};
      bf16x8 ah, al;
      split8(v, ah, al);
      const size_t qidx = (((size_t)icg * 2 + hi) * 64 + (oc0 + lo)) * 8;
      bf16x8 bh = *(const bf16x8*)(qpk_hi + qidx);
      bf16x8 bl = *(const bf16x8*)(qpk_lo + qidx);
      c = mfma32x16(ah, bh, c);
      c = mfma32x16(ah, bl, c);
      c = mfma32x16(al, bh, c);
    }
    const int oc = oc0 + lo;
    const int h = oc >> 3, d = oc & 7;
    u16* qb = qbuf + (((size_t)b * NHEAD + h) * NTOK) * HDIM + d;
    #pragma unroll
    for (int r = 0; r < 16; ++r) {
      const int tok = tok0 + (r & 3) + 8 * (r >> 2) + 4 * hi;
      qb[(size_t)tok * HDIM] = f2bf(c[r]);
    }
  }
}

// ---------------- K2 v2: widened to 256 threads (4 tokens/block, 1 wave each).
// Per-token math identical to r13 k2. Per-wave LDS slice.
__global__ __launch_bounds__(256) void k2_ln_kv(const float* __restrict__ pbuf,
                                                const float* __restrict__ srb,
                                                const float* __restrict__ lng,
                                                const float* __restrict__ lnb,
                                                const float* __restrict__ kvw,
                                                u16* __restrict__ kbuf,
                                                u16* __restrict__ vbufT) {
  __shared__ float ylds[4][64];
  const int t = threadIdx.x;
  const int wv = t >> 6;                       // wave = token slot
  const int o  = t & 63;                       // channel
  const int tg = blockIdx.x * 4 + wv;          // 0..511 reduced token
  float y = srb[o];
  #pragma unroll 8
  for (int s = 0; s < NSLICE; ++s) y += pbuf[((size_t)s * RTOKS + tg) * 64 + o];
  const float sum   = wave_reduce_sum64(y);
  const float sumsq = wave_reduce_sum64(y * y);
  const float mu  = sum * (1.f / 64.f);
  const float var = sumsq * (1.f / 64.f) - mu * mu;
  const float rstd = rsqrtf(var + 1e-5f);
  const float yn = (y - mu) * rstd * lng[o] + lnb[o];
  ylds[wv][o] = yn;
  __syncthreads();
  float ka = 0.f, va = 0.f;
  #pragma unroll 16
  for (int i = 0; i < 64; ++i) {
    const float yv = ylds[wv][i];
    ka += yv * kvw[i * 128 + o];
    va += yv * kvw[i * 128 + 64 + o];
  }
  const int b = tg >> 8, pp = tg & 255;
  const int h = o >> 3, d = o & 7;
  const int bh = b * NHEAD + h;
  kbuf[((size_t)bh * NKV + pp) * HDIM + d] = f2bf(ka * KSCALE);
  vbufT[((size_t)bh * HDIM + d) * NKV + pp] = f2bf(va);
}

// ---------------- K4 v8 (r13): twin-tile interleave, ones-row denominator.
__global__ __launch_bounds__(256) void k4_attn_mfma(const u16* __restrict__ qbuf,
                                                    const u16* __restrict__ kbuf,
                                                    const u16* __restrict__ vbufT,
                                                    float* __restrict__ abuf) {
  const int t = threadIdx.x;
  const int lane = t & 63;
  const int w = blockIdx.x * 4 + (t >> 6);   // global wave id, 0..2047
  const int bh = w >> 7;                     // 16 (b,h) pairs, 128 waves each
  const int wi = w & 127;
  const int lo = lane & 31;
  const int hi = lane >> 5;

  bf16x8 kf[8];
  const u16* kb = kbuf + (size_t)bh * NKV * HDIM;
  #pragma unroll
  for (int c = 0; c < 8; ++c) {
    bf16x8 z = {0, 0, 0, 0, 0, 0, 0, 0};
    if (hi == 0) z = *(const bf16x8*)(kb + (c * 32 + lo) * HDIM);
    kf[c] = z;
  }

  const short one_bf = (short)0x3F80;
  bf16x8 vf[16];
  const u16* vb = vbufT + (size_t)bh * HDIM * NKV;
  #pragma unroll
  for (int f = 0; f < 16; ++f) {
    bf16x8 z = {0, 0, 0, 0, 0, 0, 0, 0};
    if (lo < 8) {
      z = *(const bf16x8*)(vb + lo * NKV + f * 16 + hi * 8);
    } else if (lo == 8) {
      bf16x8 o1 = {one_bf, one_bf, one_bf, one_bf, one_bf, one_bf, one_bf, one_bf};
      z = o1;
    }
    vf[f] = z;
  }

  #pragma unroll
  for (int cp = 0; cp < 2; ++cp) {
    const int qtA = (wi * 4 + cp * 2) * 32;
    const int qtB = qtA + 32;
    bf16x8 qfA = {0, 0, 0, 0, 0, 0, 0, 0};
    bf16x8 qfB = {0, 0, 0, 0, 0, 0, 0, 0};
    if (hi == 0) {
      qfA = *(const bf16x8*)(qbuf + ((size_t)bh * NTOK + qtA + lo) * HDIM);
      qfB = *(const bf16x8*)(qbuf + ((size_t)bh * NTOK + qtB + lo) * HDIM);
    }

    f32x16 oA, oB;
    #pragma unroll
    for (int i = 0; i < 16; ++i) { oA[i] = 0.f; oB[i] = 0.f; }

    #pragma unroll
    for (int kblk = 0; kblk < 8; ++kblk) {
      f32x16 sA, sB;
      #pragma unroll
      for (int i = 0; i < 16; ++i) { sA[i] = 0.f; sB[i] = 0.f; }
      sA = mfma32x16(kf[kblk], qfA, sA);
      sB = mfma32x16(kf[kblk], qfB, sB);

      #pragma unroll
      for (int r = 0; r < 16; ++r) sA[r] = fexp2(sA[r]);
      #pragma unroll
      for (int r = 0; r < 16; ++r) sB[r] = fexp2(sB[r]);

      unsigned pkA01[4], pkA23[4], pkB01[4], pkB23[4];
      #pragma unroll
      for (int q = 0; q < 4; ++q) {
        asm("v_cvt_pk_bf16_f32 %0, %1, %2" : "=v"(pkA01[q]) : "v"(sA[4*q+0]), "v"(sA[4*q+1]));
        asm("v_cvt_pk_bf16_f32 %0, %1, %2" : "=v"(pkA23[q]) : "v"(sA[4*q+2]), "v"(sA[4*q+3]));
      }
      #pragma unroll
      for (int q = 0; q < 4; ++q) {
        asm("v_cvt_pk_bf16_f32 %0, %1, %2" : "=v"(pkB01[q]) : "v"(sB[4*q+0]), "v"(sB[4*q+1]));
        asm("v_cvt_pk_bf16_f32 %0, %1, %2" : "=v"(pkB23[q]) : "v"(sB[4*q+2]), "v"(sB[4*q+3]));
      }
      #pragma unroll
      for (int jj = 0; jj < 2; ++jj) {
        unsigned a0 = pkA01[2*jj], b0 = pkA01[2*jj+1];
        unsigned a1 = pkA23[2*jj], b1 = pkA23[2*jj+1];
        pl32swap(a0, b0);
        pl32swap(a1, b1);
        u32x4 wv; wv[0] = a0; wv[1] = a1; wv[2] = b0; wv[3] = b1;
        bf16x8 pfrag = __builtin_bit_cast(bf16x8, wv);
        oA = mfma32x16(vf[kblk * 2 + jj], pfrag, oA);
      }
      #pragma unroll
      for (int jj = 0; jj < 2; ++jj) {
        unsigned a0 = pkB01[2*jj], b0 = pkB01[2*jj+1];
        unsigned a1 = pkB23[2*jj], b1 = pkB23[2*jj+1];
        pl32swap(a0, b0);
        pl32swap(a1, b1);
        u32x4 wv; wv[0] = a0; wv[1] = a1; wv[2] = b0; wv[3] = b1;
        bf16x8 pfrag = __builtin_bit_cast(bf16x8, wv);
        oB = mfma32x16(vf[kblk * 2 + jj], pfrag, oB);
      }
    }

    {
      float d0 = oA[4];
      float d1 = __shfl_xor(d0, 32, 64);
      const float den = hi ? d1 : d0;
      const float r = 1.0f / den;
      float4 o;
      o.x = oA[0] * r; o.y = oA[1] * r; o.z = oA[2] * r; o.w = oA[3] * r;
      *(float4*)(abuf + ((size_t)bh * NTOK + qtA + lo) * HDIM + hi * 4) = o;
    }
    {
      float d0 = oB[4];
      float d1 = __shfl_xor(d0, 32, 64);
      const float den = hi ? d1 : d0;
      const float r = 1.0f / den;
      float4 o;
      o.x = oB[0] * r; o.y = oB[1] * r; o.z = oB[2] * r; o.w = oB[3] * r;
      *(float4*)(abuf + ((size_t)bh * NTOK + qtB + lo) * HDIM + hi * 4) = o;
    }
  }
}

// ---------------- kP: out = O @ pw + pb via split-bf16 MFMA.
__global__ __launch_bounds__(256) void kP_proj(const float* __restrict__ abuf,
                                               const u16* __restrict__ ppk_hi,
                                               const u16* __restrict__ ppk_lo,
                                               const float* __restrict__ pb,
                                               float* __restrict__ out) {
  const int t = threadIdx.x;
  const int lane = t & 63;
  const int lo = lane & 31;
  const int hi = lane >> 5;
  const int w = t >> 6;
  const int oc0 = (w & 1) * 32;
  const int blk = blockIdx.x;
  const int b = blk >> 8;
  const int tok0 = ((blk & 255) * 2 + (w >> 1)) * 32;

  f32x16 c;
  #pragma unroll
  for (int i = 0; i < 16; ++i) c[i] = 0.f;

  #pragma unroll
  for (int f = 0; f < 4; ++f) {
    const int h = 2 * f + hi;                 // attention-output channel group = head
    const float* src = abuf + (((size_t)b * NHEAD + h) * NTOK + tok0 + lo) * HDIM;
    float4 a0 = *(const float4*)(src);
    float4 a1 = *(const float4*)(src + 4);
    float v[8] = {a0.x, a0.y, a0.z, a0.w, a1.x, a1.y, a1.z, a1.w};
    bf16x8 ah, al;
    split8(v, ah, al);
    const size_t pidx = (((size_t)f * 2 + hi) * 64 + (oc0 + lo)) * 8;
    bf16x8 bh = *(const bf16x8*)(ppk_hi + pidx);
    bf16x8 bl = *(const bf16x8*)(ppk_lo + pidx);
    c = mfma32x16(ah, bh, c);
    c = mfma32x16(ah, bl, c);
    c = mfma32x16(al, bh, c);
  }
  const float pbv = pb[oc0 + lo];
  #pragma unroll
  for (int r = 0; r < 16; ++r) {
    const int tok = tok0 + (r & 3) + 8 * (r >> 2) + 4 * hi;
    out[((size_t)b * NTOK + tok) * CDIM + oc0 + lo] = c[r] + pbv;
  }
}

extern "C" void kernel_launch(void* const* d_in, const int* in_sizes, int n_in,
                              void* d_out, int out_size, void* d_ws, size_t ws_size,
                              hipStream_t stream) {
  const float* x    = (const float*)d_in[0];
  // d_in[1], d_in[2] are H, W scalars (128, 128) — fixed by the problem
  const float* qw   = (const float*)d_in[3];
  const float* kvw  = (const float*)d_in[4];
  const float* srw  = (const float*)d_in[5];
  const float* srb  = (const float*)d_in[6];
  const float* lng  = (const float*)d_in[7];
  const float* lnb  = (const float*)d_in[8];
  const float* pw   = (const float*)d_in[9];
  const float* pb   = (const float*)d_in[10];
  float* out = (float*)d_out;
  char* base = (char*)d_ws;

  u16*   wpk_hi = (u16*)(base);               // 524288 B
  u16*   wpk_lo = (u16*)(base + 524288);      // 524288 B
  u16*   qpk_hi = (u16*)(base + 1048576);     // 8192 B
  u16*   qpk_lo = (u16*)(base + 1056768);     // 8192 B
  u16*   ppk_hi = (u16*)(base + 1064960);     // 8192 B
  u16*   ppk_lo = (u16*)(base + 1073152);     // 8192 B
  float* pbuf   = (float*)(base + 1081344);   // 32*512*64 f32 = 4194304 B
  u16*   kbuf   = (u16*)(base + 5275648);     // 65536 B
  u16*   vbufT  = (u16*)(base + 5341184);     // 65536 B
  u16*   qbuf   = (u16*)(base + 5406720);     // 4194304 B
  float* abuf   = (float*)(base + 9601024);   // 8388608 B

  k0_pack<<<1056, 256, 0, stream>>>(srw, qw, pw, wpk_hi, wpk_lo,
                                    qpk_hi, qpk_lo, ppk_hi, ppk_lo);
  kAQ_conv_qproj<<<768, 256, 0, stream>>>(x, wpk_hi, wpk_lo, qpk_hi, qpk_lo,
                                          pbuf, qbuf);
  k2_ln_kv<<<128, 256, 0, stream>>>(pbuf, srb, lng, lnb, kvw, kbuf, vbufT);
  k4_attn_mfma<<<512, 256, 0, stream>>>(qbuf, kbuf, vbufT, abuf);
  kP_proj<<<512, 256, 0, stream>>>(abuf, ppk_hi, ppk_lo, pb, out);
}

// Round 17
// 41.293 us; speedup vs baseline: 1.4357x; 1.0173x over previous
//
#include <hip/hip_runtime.h>
#include <math.h>

#define NB 2
#define NTOK 16384
#define CDIM 64
#define WIMG 128
#define NKV 256
#define NHEAD 8
#define HDIM 8
#define RTOKS 512   // NB*NKV reduced tokens
#define NSLICE 32   // conv partial slices (16 kchunks x 2 tap-pairs)

typedef unsigned short u16;
typedef __attribute__((ext_vector_type(8))) short bf16x8;
typedef __attribute__((ext_vector_type(4))) unsigned int u32x4;
typedef __attribute__((ext_vector_type(2))) unsigned int u32x2;
typedef __attribute__((ext_vector_type(16))) float f32x16;

// softmax scale folded with log2(e), applied to K before bf16 quantization
constexpr float KSCALE = 0.35355339059327373f * 1.4426950408889634f;

__device__ __forceinline__ u16 f2bf(float f) {   // RNE f32->bf16
  unsigned u = __builtin_bit_cast(unsigned, f);
  return (u16)((u + 0x7FFFu + ((u >> 16) & 1u)) >> 16);
}
__device__ __forceinline__ float bf2f(u16 h) {
  return __builtin_bit_cast(float, (unsigned)h << 16);
}

__device__ __forceinline__ f32x16 mfma32x16(bf16x8 a, bf16x8 b, f32x16 c) {
  return __builtin_amdgcn_mfma_f32_32x32x16_bf16(a, b, c, 0, 0, 0);
}

__device__ __forceinline__ void pl32swap(unsigned &a, unsigned &b) {
  u32x2 r = __builtin_amdgcn_permlane32_swap(a, b, false, false);
  a = r[0]; b = r[1];
}

__device__ __forceinline__ float fexp2(float x) {
  float r;
  asm("v_exp_f32 %0, %1" : "=v"(r) : "v"(x));
  return r;
}

// split 8 f32 into hi/lo bf16 fragments: v ~= hi + lo
__device__ __forceinline__ void split8(const float* v, bf16x8& hout, bf16x8& lout) {
  unsigned hw[4], lw[4];
  float hf[8], lof[8];
  #pragma unroll
  for (int q = 0; q < 4; ++q)
    asm("v_cvt_pk_bf16_f32 %0, %1, %2" : "=v"(hw[q]) : "v"(v[2*q]), "v"(v[2*q+1]));
  #pragma unroll
  for (int q = 0; q < 4; ++q) {
    hf[2*q]   = __builtin_bit_cast(float, hw[q] << 16);
    hf[2*q+1] = __builtin_bit_cast(float, hw[q] & 0xFFFF0000u);
  }
  #pragma unroll
  for (int j = 0; j < 8; ++j) lof[j] = v[j] - hf[j];
  #pragma unroll
  for (int q = 0; q < 4; ++q)
    asm("v_cvt_pk_bf16_f32 %0, %1, %2" : "=v"(lw[q]) : "v"(lof[2*q]), "v"(lof[2*q+1]));
  u32x4 H; H[0] = hw[0]; H[1] = hw[1]; H[2] = hw[2]; H[3] = hw[3];
  u32x4 L; L[0] = lw[0]; L[1] = lw[1]; L[2] = lw[2]; L[3] = lw[3];
  hout = __builtin_bit_cast(bf16x8, H);
  lout = __builtin_bit_cast(bf16x8, L);
}

__device__ __forceinline__ float wave_reduce_sum64(float v) {
  #pragma unroll
  for (int off = 32; off > 0; off >>= 1) v += __shfl_xor(v, off, 64);
  return v;
}

// ---------------- k0p: pack all weights into MFMA-B-operand bf16 hi/lo layouts.
__global__ __launch_bounds__(256) void k0_pack(const float* __restrict__ srw,
                                               const float* __restrict__ qw,
                                               const float* __restrict__ pw,
                                               u16* __restrict__ wpk_hi, u16* __restrict__ wpk_lo,
                                               u16* __restrict__ qpk_hi, u16* __restrict__ qpk_lo,
                                               u16* __restrict__ ppk_hi, u16* __restrict__ ppk_lo) {
  int idx = blockIdx.x * 256 + threadIdx.x;   // 270336 total = 1056*256
  if (idx < 262144) {
    const int j   = idx & 7;
    const int oc  = (idx >> 3) & 63;
    const int hi  = (idx >> 9) & 1;
    const int icg = (idx >> 10) & 3;
    const int s   = idx >> 12;
    const float v = srw[oc * 4096 + (icg * 16 + hi * 8 + j) * 64 + s];
    const u16 h = f2bf(v);
    wpk_hi[idx] = h;
    wpk_lo[idx] = f2bf(v - bf2f(h));
  } else if (idx < 262144 + 4096) {
    const int q = idx - 262144;
    const int j   = q & 7;
    const int o   = (q >> 3) & 63;
    const int hi  = (q >> 9) & 1;
    const int icg = q >> 10;
    const float v = qw[(icg * 16 + hi * 8 + j) * 64 + o];
    const u16 h = f2bf(v);
    qpk_hi[q] = h;
    qpk_lo[q] = f2bf(v - bf2f(h));
  } else if (idx < 262144 + 8192) {
    const int q = idx - 262144 - 4096;
    const int j  = q & 7;
    const int o  = (q >> 3) & 63;
    const int hi = (q >> 9) & 1;
    const int g  = q >> 10;
    const float v = pw[(g * 16 + hi * 8 + j) * 64 + o];
    const u16 h = f2bf(v);
    ppk_hi[q] = h;
    ppk_lo[q] = f2bf(v - bf2f(h));
  }
}

// ---------------- kAQ: merged conv-partials + q-proj (independent after k0p).
// blocks 0..255: conv (tile = blk&15, kc = blk>>4). blocks 256..767: q-proj.
__global__ __launch_bounds__(256) void kAQ_conv_qproj(const float* __restrict__ x,
                                                      const u16* __restrict__ wpk_hi,
                                                      const u16* __restrict__ wpk_lo,
                                                      const u16* __restrict__ qpk_hi,
                                                      const u16* __restrict__ qpk_lo,
                                                      float* __restrict__ pbuf,
                                                      u16* __restrict__ qbuf) {
  const int t = threadIdx.x;
  const int lane = t & 63;
  const int lo = lane & 31;
  const int hi = lane >> 5;
  const int w = t >> 6;
  const int oc0 = (w & 1) * 32;
  const int blk = blockIdx.x;

  if (blk < 256) {
    // ---- conv partials (r13 kA2 verbatim math)
    const int th = w >> 1;                  // tap-pair within chunk
    const int tile = blk & 15;
    const int kc = blk >> 4;
    const int tg = tile * 32 + lo;          // reduced token (A-row m)
    const int b = tg >> 8;
    const int p = tg & 255;

    f32x16 c;
    #pragma unroll
    for (int i = 0; i < 16; ++i) c[i] = 0.f;

    #pragma unroll
    for (int sp = 0; sp < 2; ++sp) {
      const int s = kc * 4 + th * 2 + sp;   // conv tap 0..63
      const int kh = s >> 3, kw = s & 7;
      const int nrow = ((p >> 4) * 8 + kh) * WIMG + (p & 15) * 8 + kw;
      const float* xr = x + ((size_t)b * NTOK + nrow) * CDIM;
      #pragma unroll
      for (int icg = 0; icg < 4; ++icg) {
        const int ic0 = icg * 16 + hi * 8;
        float4 a0 = *(const float4*)(xr + ic0);
        float4 a1 = *(const float4*)(xr + ic0 + 4);
        float v[8] = {a0.x, a0.y, a0.z, a0.w, a1.x, a1.y, a1.z, a1.w};
        bf16x8 ah, al;
        split8(v, ah, al);
        const size_t widx = ((((size_t)s * 4 + icg) * 2 + hi) * 64 + (oc0 + lo)) * 8;
        bf16x8 bh = *(const bf16x8*)(wpk_hi + widx);
        bf16x8 bl = *(const bf16x8*)(wpk_lo + widx);
        c = mfma32x16(ah, bh, c);
        c = mfma32x16(ah, bl, c);
        c = mfma32x16(al, bh, c);
      }
    }
    const int slice = kc * 2 + th;
    #pragma unroll
    for (int r = 0; r < 16; ++r) {
      const int tokr = (r & 3) + 8 * (r >> 2) + 4 * hi;   // verified C row map
      pbuf[((size_t)slice * RTOKS + tile * 32 + tokr) * 64 + oc0 + lo] = c[r];
    }
  } else {
    // ---- q-proj (r13 kQ verbatim math)
    const int qblk = blk - 256;             // 0..511
    const int b = qblk >> 8;
    const int tok0 = ((qblk & 255) * 2 + (w >> 1)) * 32;

    f32x16 c;
    #pragma unroll
    for (int i = 0; i < 16; ++i) c[i] = 0.f;

    const float* xr = x + ((size_t)b * NTOK + tok0 + lo) * CDIM;
    #pragma unroll
    for (int icg = 0; icg < 4; ++icg) {
      const int ic0 = icg * 16 + hi * 8;
      float4 a0 = *(const float4*)(xr + ic0);
      float4 a1 = *(const float4*)(xr + ic0 + 4);
      float v[8] = {a0.x, a0.y, a0.z, a0.w, a1.x, a1.y, a1.z, a1.w};
      bf16x8 ah, al;
      split8(v, ah, al);
      const size_t qidx = (((size_t)icg * 2 + hi) * 64 + (oc0 + lo)) * 8;
      bf16x8 bh = *(const bf16x8*)(qpk_hi + qidx);
      bf16x8 bl = *(const bf16x8*)(qpk_lo + qidx);
      c = mfma32x16(ah, bh, c);
      c = mfma32x16(ah, bl, c);
      c = mfma32x16(al, bh, c);
    }
    const int oc = oc0 + lo;
    const int h = oc >> 3, d = oc & 7;
    u16* qb = qbuf + (((size_t)b * NHEAD + h) * NTOK) * HDIM + d;
    #pragma unroll
    for (int r = 0; r < 16; ++r) {
      const int tok = tok0 + (r & 3) + 8 * (r >> 2) + 4 * hi;
      qb[(size_t)tok * HDIM] = f2bf(c[r]);
    }
  }
}

// ---------------- K2 v2: 256 threads (4 tokens/block, 1 wave each).
__global__ __launch_bounds__(256) void k2_ln_kv(const float* __restrict__ pbuf,
                                                const float* __restrict__ srb,
                                                const float* __restrict__ lng,
                                                const float* __restrict__ lnb,
                                                const float* __restrict__ kvw,
                                                u16* __restrict__ kbuf,
                                                u16* __restrict__ vbufT) {
  __shared__ float ylds[4][64];
  const int t = threadIdx.x;
  const int wv = t >> 6;                       // wave = token slot
  const int o  = t & 63;                       // channel
  const int tg = blockIdx.x * 4 + wv;          // 0..511 reduced token
  float y = srb[o];
  #pragma unroll 8
  for (int s = 0; s < NSLICE; ++s) y += pbuf[((size_t)s * RTOKS + tg) * 64 + o];
  const float sum   = wave_reduce_sum64(y);
  const float sumsq = wave_reduce_sum64(y * y);
  const float mu  = sum * (1.f / 64.f);
  const float var = sumsq * (1.f / 64.f) - mu * mu;
  const float rstd = rsqrtf(var + 1e-5f);
  const float yn = (y - mu) * rstd * lng[o] + lnb[o];
  ylds[wv][o] = yn;
  __syncthreads();
  float ka = 0.f, va = 0.f;
  #pragma unroll 16
  for (int i = 0; i < 64; ++i) {
    const float yv = ylds[wv][i];
    ka += yv * kvw[i * 128 + o];
    va += yv * kvw[i * 128 + 64 + o];
  }
  const int b = tg >> 8, pp = tg & 255;
  const int h = o >> 3, d = o & 7;
  const int bh = b * NHEAD + h;
  kbuf[((size_t)bh * NKV + pp) * HDIM + d] = f2bf(ka * KSCALE);
  vbufT[((size_t)bh * HDIM + d) * NKV + pp] = f2bf(va);
}

// ---------------- K4 v10: twin-tile ILP, grid 1024, in-loop vf prefetch.
// NO min-waves launch_bounds arg (empirical NaN carrier: r5/r6/r7/r16).
// vf preloads dropped (~48 VGPR) so natural allocation may reach 3 waves/SIMD.
// Per-tile arithmetic sequence identical to r13 -> bit-identical output.
__global__ __launch_bounds__(256) void k4_attn_mfma(const u16* __restrict__ qbuf,
                                                    const u16* __restrict__ kbuf,
                                                    const u16* __restrict__ vbufT,
                                                    float* __restrict__ abuf) {
  const int t = threadIdx.x;
  const int lane = t & 63;
  const int w = blockIdx.x * 4 + (t >> 6);   // global wave id, 0..4095
  const int bh = w >> 8;                     // 16 (b,h) pairs, 256 waves each
  const int wi = w & 255;                    // twin-pair index
  const int lo = lane & 31;
  const int hi = lane >> 5;

  const u16* kb = kbuf + (size_t)bh * NKV * HDIM;
  const u16* vb = vbufT + (size_t)bh * HDIM * NKV;

  bf16x8 kf[8];
  #pragma unroll
  for (int c = 0; c < 8; ++c) {
    bf16x8 z = {0, 0, 0, 0, 0, 0, 0, 0};
    if (hi == 0) z = *(const bf16x8*)(kb + (c * 32 + lo) * HDIM);
    kf[c] = z;
  }

  const int qtA = (wi * 2) * 32;
  const int qtB = qtA + 32;
  bf16x8 qfA = {0, 0, 0, 0, 0, 0, 0, 0};
  bf16x8 qfB = {0, 0, 0, 0, 0, 0, 0, 0};
  if (hi == 0) {
    qfA = *(const bf16x8*)(qbuf + ((size_t)bh * NTOK + qtA + lo) * HDIM);
    qfB = *(const bf16x8*)(qbuf + ((size_t)bh * NTOK + qtB + lo) * HDIM);
  }

  f32x16 oA, oB;
  #pragma unroll
  for (int i = 0; i < 16; ++i) { oA[i] = 0.f; oB[i] = 0.f; }

  // V_aug^T fragments: rows 0..7 = V^T (in-loop prefetch), row 8 = ones, rows 9+ = 0
  const short one_bf = (short)0x3F80;
  const bf16x8 vzero = {0, 0, 0, 0, 0, 0, 0, 0};
  const bf16x8 vones = {one_bf, one_bf, one_bf, one_bf, one_bf, one_bf, one_bf, one_bf};
  bf16x8 vf0n = (lo == 8) ? vones : vzero;
  bf16x8 vf1n = vf0n;
  if (lo < 8) {
    vf0n = *(const bf16x8*)(vb + lo * NKV + 0 + hi * 8);
    vf1n = *(const bf16x8*)(vb + lo * NKV + 16 + hi * 8);
  }

  #pragma unroll
  for (int kblk = 0; kblk < 8; ++kblk) {
    const bf16x8 vf0 = vf0n;
    const bf16x8 vf1 = vf1n;
    if (kblk < 7 && lo < 8) {   // prefetch next kblk's V fragments
      vf0n = *(const bf16x8*)(vb + lo * NKV + (kblk + 1) * 32 + hi * 8);
      vf1n = *(const bf16x8*)(vb + lo * NKV + (kblk + 1) * 32 + 16 + hi * 8);
    }

    f32x16 sA, sB;
    #pragma unroll
    for (int i = 0; i < 16; ++i) { sA[i] = 0.f; sB[i] = 0.f; }
    sA = mfma32x16(kf[kblk], qfA, sA);
    sB = mfma32x16(kf[kblk], qfB, sB);

    #pragma unroll
    for (int r = 0; r < 16; ++r) sA[r] = fexp2(sA[r]);
    #pragma unroll
    for (int r = 0; r < 16; ++r) sB[r] = fexp2(sB[r]);

    unsigned pkA01[4], pkA23[4], pkB01[4], pkB23[4];
    #pragma unroll
    for (int q = 0; q < 4; ++q) {
      asm("v_cvt_pk_bf16_f32 %0, %1, %2" : "=v"(pkA01[q]) : "v"(sA[4*q+0]), "v"(sA[4*q+1]));
      asm("v_cvt_pk_bf16_f32 %0, %1, %2" : "=v"(pkA23[q]) : "v"(sA[4*q+2]), "v"(sA[4*q+3]));
    }
    #pragma unroll
    for (int q = 0; q < 4; ++q) {
      asm("v_cvt_pk_bf16_f32 %0, %1, %2" : "=v"(pkB01[q]) : "v"(sB[4*q+0]), "v"(sB[4*q+1]));
      asm("v_cvt_pk_bf16_f32 %0, %1, %2" : "=v"(pkB23[q]) : "v"(sB[4*q+2]), "v"(sB[4*q+3]));
    }
    {
      unsigned a0 = pkA01[0], b0 = pkA01[1];
      unsigned a1 = pkA23[0], b1 = pkA23[1];
      pl32swap(a0, b0);
      pl32swap(a1, b1);
      u32x4 wv; wv[0] = a0; wv[1] = a1; wv[2] = b0; wv[3] = b1;
      bf16x8 pfrag = __builtin_bit_cast(bf16x8, wv);
      oA = mfma32x16(vf0, pfrag, oA);
    }
    {
      unsigned a0 = pkA01[2], b0 = pkA01[3];
      unsigned a1 = pkA23[2], b1 = pkA23[3];
      pl32swap(a0, b0);
      pl32swap(a1, b1);
      u32x4 wv; wv[0] = a0; wv[1] = a1; wv[2] = b0; wv[3] = b1;
      bf16x8 pfrag = __builtin_bit_cast(bf16x8, wv);
      oA = mfma32x16(vf1, pfrag, oA);
    }
    {
      unsigned a0 = pkB01[0], b0 = pkB01[1];
      unsigned a1 = pkB23[0], b1 = pkB23[1];
      pl32swap(a0, b0);
      pl32swap(a1, b1);
      u32x4 wv; wv[0] = a0; wv[1] = a1; wv[2] = b0; wv[3] = b1;
      bf16x8 pfrag = __builtin_bit_cast(bf16x8, wv);
      oB = mfma32x16(vf0, pfrag, oB);
    }
    {
      unsigned a0 = pkB01[2], b0 = pkB01[3];
      unsigned a1 = pkB23[2], b1 = pkB23[3];
      pl32swap(a0, b0);
      pl32swap(a1, b1);
      u32x4 wv; wv[0] = a0; wv[1] = a1; wv[2] = b0; wv[3] = b1;
      bf16x8 pfrag = __builtin_bit_cast(bf16x8, wv);
      oB = mfma32x16(vf1, pfrag, oB);
    }
  }

  {
    float d0 = oA[4];
    float d1 = __shfl_xor(d0, 32, 64);
    const float den = hi ? d1 : d0;
    const float r = 1.0f / den;
    float4 o;
    o.x = oA[0] * r; o.y = oA[1] * r; o.z = oA[2] * r; o.w = oA[3] * r;
    *(float4*)(abuf + ((size_t)bh * NTOK + qtA + lo) * HDIM + hi * 4) = o;
  }
  {
    float d0 = oB[4];
    float d1 = __shfl_xor(d0, 32, 64);
    const float den = hi ? d1 : d0;
    const float r = 1.0f / den;
    float4 o;
    o.x = oB[0] * r; o.y = oB[1] * r; o.z = oB[2] * r; o.w = oB[3] * r;
    *(float4*)(abuf + ((size_t)bh * NTOK + qtB + lo) * HDIM + hi * 4) = o;
  }
}

// ---------------- kP: out = O @ pw + pb via split-bf16 MFMA.
__global__ __launch_bounds__(256) void kP_proj(const float* __restrict__ abuf,
                                               const u16* __restrict__ ppk_hi,
                                               const u16* __restrict__ ppk_lo,
                                               const float* __restrict__ pb,
                                               float* __restrict__ out) {
  const int t = threadIdx.x;
  const int lane = t & 63;
  const int lo = lane & 31;
  const int hi = lane >> 5;
  const int w = t >> 6;
  const int oc0 = (w & 1) * 32;
  const int blk = blockIdx.x;
  const int b = blk >> 8;
  const int tok0 = ((blk & 255) * 2 + (w >> 1)) * 32;

  f32x16 c;
  #pragma unroll
  for (int i = 0; i < 16; ++i) c[i] = 0.f;

  #pragma unroll
  for (int f = 0; f < 4; ++f) {
    const int h = 2 * f + hi;                 // attention-output channel group = head
    const float* src = abuf + (((size_t)b * NHEAD + h) * NTOK + tok0 + lo) * HDIM;
    float4 a0 = *(const float4*)(src);
    float4 a1 = *(const float4*)(src + 4);
    float v[8] = {a0.x, a0.y, a0.z, a0.w, a1.x, a1.y, a1.z, a1.w};
    bf16x8 ah, al;
    split8(v, ah, al);
    const size_t pidx = (((size_t)f * 2 + hi) * 64 + (oc0 + lo)) * 8;
    bf16x8 bh = *(const bf16x8*)(ppk_hi + pidx);
    bf16x8 bl = *(const bf16x8*)(ppk_lo + pidx);
    c = mfma32x16(ah, bh, c);
    c = mfma32x16(ah, bl, c);
    c = mfma32x16(al, bh, c);
  }
  const float pbv = pb[oc0 + lo];
  #pragma unroll
  for (int r = 0; r < 16; ++r) {
    const int tok = tok0 + (r & 3) + 8 * (r >> 2) + 4 * hi;
    out[((size_t)b * NTOK + tok) * CDIM + oc0 + lo] = c[r] + pbv;
  }
}

extern "C" void kernel_launch(void* const* d_in, const int* in_sizes, int n_in,
                              void* d_out, int out_size, void* d_ws, size_t ws_size,
                              hipStream_t stream) {
  const float* x    = (const float*)d_in[0];
  // d_in[1], d_in[2] are H, W scalars (128, 128) — fixed by the problem
  const float* qw   = (const float*)d_in[3];
  const float* kvw  = (const float*)d_in[4];
  const float* srw  = (const float*)d_in[5];
  const float* srb  = (const float*)d_in[6];
  const float* lng  = (const float*)d_in[7];
  const float* lnb  = (const float*)d_in[8];
  const float* pw   = (const float*)d_in[9];
  const float* pb   = (const float*)d_in[10];
  float* out = (float*)d_out;
  char* base = (char*)d_ws;

  u16*   wpk_hi = (u16*)(base);               // 524288 B
  u16*   wpk_lo = (u16*)(base + 524288);      // 524288 B
  u16*   qpk_hi = (u16*)(base + 1048576);     // 8192 B
  u16*   qpk_lo = (u16*)(base + 1056768);     // 8192 B
  u16*   ppk_hi = (u16*)(base + 1064960);     // 8192 B
  u16*   ppk_lo = (u16*)(base + 1073152);     // 8192 B
  float* pbuf   = (float*)(base + 1081344);   // 32*512*64 f32 = 4194304 B
  u16*   kbuf   = (u16*)(base + 5275648);     // 65536 B
  u16*   vbufT  = (u16*)(base + 5341184);     // 65536 B
  u16*   qbuf   = (u16*)(base + 5406720);     // 4194304 B
  float* abuf   = (float*)(base + 9601024);   // 8388608 B

  k0_pack<<<1056, 256, 0, stream>>>(srw, qw, pw, wpk_hi, wpk_lo,
                                    qpk_hi, qpk_lo, ppk_hi, ppk_lo);
  kAQ_conv_qproj<<<768, 256, 0, stream>>>(x, wpk_hi, wpk_lo, qpk_hi, qpk_lo,
                                          pbuf, qbuf);
  k2_ln_kv<<<128, 256, 0, stream>>>(pbuf, srb, lng, lnb, kvw, kbuf, vbufT);
  k4_attn_mfma<<<1024, 256, 0, stream>>>(qbuf, kbuf, vbufT, abuf);
  kP_proj<<<512, 256, 0, stream>>>(abuf, ppk_hi, ppk_lo, pb, out);
}